// Round 13
// baseline (252.681 us; speedup 1.0000x reference)
//
#include <hip/hip_runtime.h>
#include <math.h>

namespace {
constexpr int B = 8, C = 128, N = 2048, M = 512;
constexpr int NSPLIT = 8;       // part (NSPLIT*B*C*M fp32 = 16.8MB) must fit split region (25.2MB)
constexpr int MBLK = 16;        // energy m-tiles -> rowpart slots
constexpr float INV_SQRT_C = 0.08838834764831845f;  // 1/sqrt(128)
}

typedef __attribute__((ext_vector_type(8))) short short8;
typedef __attribute__((ext_vector_type(16))) float f32x16;
typedef unsigned short ushort_t;
typedef unsigned int u32;

__device__ inline ushort_t f2bf(float f) {   // round-to-nearest-even bf16
  union { float f; u32 u; } a; a.f = f;
  u32 r = a.u + 0x7fffu + ((a.u >> 16) & 1u);
  return (ushort_t)(r >> 16);
}
__device__ inline float bf2f(ushort_t h) {
  union { u32 u; float f; } a; a.u = ((u32)h) << 16; return a.f;
}

// -- q,k: 3-term bf16 split, k-chunk-major [term][b][kc][n][8]; v: bf16 [b][c][n] --
__global__ __launch_bounds__(256) void qkv_kernel(
    const float* __restrict__ x, const float* __restrict__ Wq,
    const float* __restrict__ Wk, const float* __restrict__ Wv,
    ushort_t* __restrict__ split, ushort_t* __restrict__ vbf) {
  const size_t TERM = (size_t)B * N * C;
  int kc = blockIdx.x;             // output-channel chunk (8 channels)
  int o0 = kc * 8;
  int n = blockIdx.y * 256 + threadIdx.x;
  int b = blockIdx.z;
  const float* xb = x + (size_t)b * C * N + n;
  float aq[8] = {}, ak[8] = {}, av[8] = {};
  #pragma unroll 8
  for (int c = 0; c < C; ++c) {    // unroll 8: more x-loads in flight; fmaf
    float xv = xb[(size_t)c * N];  // chains per acc stay c-ascending (bit-safe)
    #pragma unroll
    for (int j = 0; j < 8; ++j) {  // W loads wave-uniform -> s_loads
      aq[j] = fmaf(Wq[(o0 + j) * C + c], xv, aq[j]);
      ak[j] = fmaf(Wk[(o0 + j) * C + c], xv, ak[j]);
      av[j] = fmaf(Wv[(o0 + j) * C + c], xv, av[j]);
    }
  }
  #pragma unroll
  for (int j = 0; j < 8; ++j)
    vbf[((size_t)b * C + o0 + j) * N + n] = f2bf(av[j]);
  size_t rowoff = ((size_t)b * 16 + kc) * (size_t)N * 8 + (size_t)n * 8;
  #pragma unroll
  for (int tt = 0; tt < 3; ++tt) {
    short8 qv, kv;
    #pragma unroll
    for (int j = 0; j < 8; ++j) {
      ushort_t h = f2bf(aq[j]); qv[j] = (short)h; aq[j] -= bf2f(h);
      h = f2bf(ak[j]);          kv[j] = (short)h; ak[j] -= bf2f(h);
    }
    *(short8*)&split[tt * TERM + rowoff]       = qv;
    *(short8*)&split[(3 + tt) * TERM + rowoff] = kv;
  }
}

// ---- Ae[b,n,m] = exp(q.k/sqrt(C)) via 6-product 3-term-split MFMA ------
// FROZEN (r5/r10 text verbatim): selection-path bits depend on this exact
// arithmetic order. Do not reorder MFMAs, exp, or the LDS reduce.
__global__ __launch_bounds__(256) void energy_kernel(
    const ushort_t* __restrict__ split,
    float* __restrict__ Ae, float* __restrict__ rowpart) {
  __shared__ float red[128][64];   // 32 KB
  __shared__ float red2[128][2];
  const size_t TERM = (size_t)B * N * C;
  const size_t ROW8 = (size_t)N * 8;       // elements per kc-row
  int t = threadIdx.x;
  int lane = t & 63, w = t >> 6;
  int wn = w & 1, wm = w >> 1;             // wave quadrant
  // 4x4 supertile swizzle for L2 locality
  int lin = blockIdx.y * 16 + blockIdx.x;
  int st = lin >> 4, wi = lin & 15;
  int mb = (st & 3) * 4 + (wi & 3);
  int nb = (st >> 2) * 4 + (wi >> 2);
  int m0 = mb * 128, n0 = nb * 128, b = blockIdx.z;
  int lr = lane & 31, lq = lane >> 5;
  size_t kbase = ((size_t)b * 16 + lq) * ROW8;
  const ushort_t* Abase = split + kbase + (size_t)(n0 + wn * 64 + lr) * 8;
  const ushort_t* Bbase = split + 3 * TERM + kbase + (size_t)(m0 + wm * 64 + lr) * 8;
  f32x16 acc[2][2] = {};
  #pragma unroll
  for (int s = 0; s < 8; ++s) {            // K = 8 steps x 16
    size_t so = (size_t)s * 2 * ROW8;
    short8 aT[3][2], bT[3][2];
    #pragma unroll
    for (int tt = 0; tt < 3; ++tt)
      #pragma unroll
      for (int i = 0; i < 2; ++i) {        // i = 32-point sub-tile
        aT[tt][i] = *(const short8*)(Abase + tt * TERM + so + i * 256);
        bT[tt][i] = *(const short8*)(Bbase + tt * TERM + so + i * 256);
      }
    #pragma unroll
    for (int mt = 0; mt < 2; ++mt)
      #pragma unroll
      for (int nt = 0; nt < 2; ++nt) {
        acc[mt][nt] = __builtin_amdgcn_mfma_f32_32x32x16_bf16(aT[0][mt], bT[0][nt], acc[mt][nt], 0, 0, 0);
        acc[mt][nt] = __builtin_amdgcn_mfma_f32_32x32x16_bf16(aT[1][mt], bT[0][nt], acc[mt][nt], 0, 0, 0);
        acc[mt][nt] = __builtin_amdgcn_mfma_f32_32x32x16_bf16(aT[0][mt], bT[1][nt], acc[mt][nt], 0, 0, 0);
        acc[mt][nt] = __builtin_amdgcn_mfma_f32_32x32x16_bf16(aT[2][mt], bT[0][nt], acc[mt][nt], 0, 0, 0);
        acc[mt][nt] = __builtin_amdgcn_mfma_f32_32x32x16_bf16(aT[1][mt], bT[1][nt], acc[mt][nt], 0, 0, 0);
        acc[mt][nt] = __builtin_amdgcn_mfma_f32_32x32x16_bf16(aT[0][mt], bT[2][nt], acc[mt][nt], 0, 0, 0);
      }
  }
  int lc = lr;
  #pragma unroll
  for (int mt = 0; mt < 2; ++mt) {
    #pragma unroll
    for (int reg = 0; reg < 16; ++reg) {
      int row = (reg & 3) + 8 * (reg >> 2) + 4 * lq;   // C/D layout (m74/m101)
      int rloc = wn * 64 + mt * 32 + row;
      float e0 = expf(acc[mt][0][reg] * INV_SQRT_C);
      float e1 = expf(acc[mt][1][reg] * INV_SQRT_C);
      float* pA = Ae + ((size_t)b * N + n0 + rloc) * N + m0 + wm * 64 + lc;
      pA[0] = e0; pA[32] = e1;
      red[rloc][wm * 32 + lc] = e0 + e1;   // disjoint slots, no race
    }
  }
  __syncthreads();
  {
    int row = t >> 1, h = t & 1;
    float ssum = 0.f;
    #pragma unroll
    for (int j0 = 0; j0 < 32; ++j0) {
      int j = (j0 + (t & 31)) & 31;        // bank rotation: 2-way max (free)
      ssum += red[row][h * 32 + j];
    }
    red2[row][h] = ssum;
  }
  __syncthreads();
  if (t < 128)
    rowpart[(size_t)mb * (B * N) + b * N + n0 + t] = red2[t][0] + red2[t][1];
}

// --- selpart[nch][b*N+m] = sum_{n in chunk} Ae[b,n,m] * invr[b,n] ------
// FROZEN arithmetic. invr inline (ascending 16-slot fp32 sum + 1/s).
// unroll 16 only widens the load window; dependent fmaf chain unchanged.
__global__ __launch_bounds__(256) void colsum_kernel(
    const float* __restrict__ Ae, const float* __restrict__ rowpart,
    float* __restrict__ selpart) {
  __shared__ float sinv[256];
  int t = threadIdx.x;
  int m = blockIdx.x * 256 + t;
  int nch = blockIdx.y, b = blockIdx.z;
  int n0 = nch * (N / 8);
  {
    int n = n0 + t;                  // 256 threads <-> 256 chunk rows
    float s = 0.f;
    #pragma unroll
    for (int sl = 0; sl < MBLK; ++sl)
      s += rowpart[(size_t)sl * (B * N) + b * N + n];
    sinv[t] = 1.0f / s;
  }
  __syncthreads();
  const float* Ab = Ae + (size_t)b * N * N;
  float acc = 0.f;
  #pragma unroll 16
  for (int n = n0; n < n0 + N / 8; ++n)
    acc = fmaf(Ab[(size_t)n * N + m], sinv[n - n0], acc);
  selpart[(size_t)nch * (B * N) + b * N + m] = acc;
}

// -- exact stable-descending top-k; selred fused with the SAME ascending
// 8-chunk sum order as r5's selred (bit-identical sel). Compare loop reads
// LDS via float4 (b128); r is an int count -> order-free, bit-safe.
__global__ __launch_bounds__(256) void topk_kernel(
    const float* __restrict__ selpart, int* __restrict__ idx) {
  __shared__ float s[N];
  __shared__ int rsum[64][4];
  int b = blockIdx.y;
  int t = threadIdx.x;
  for (int i = t; i < N; i += 256) {
    float v_ = 0.f;
    #pragma unroll
    for (int nch = 0; nch < 8; ++nch)
      v_ += selpart[(size_t)nch * (B * N) + b * N + i];
    s[i] = v_;
  }
  __syncthreads();
  int i = blockIdx.x * 64 + (t & 63);
  int jc = t >> 6;
  float val = s[i];
  int r = 0;
  #pragma unroll 8
  for (int j = jc * 512; j < jc * 512 + 512; j += 4) {
    float4 sj = *(const float4*)&s[j];
    r += (sj.x > val || (sj.x == val && (j + 0) < i)) ? 1 : 0;
    r += (sj.y > val || (sj.y == val && (j + 1) < i)) ? 1 : 0;
    r += (sj.z > val || (sj.z == val && (j + 2) < i)) ? 1 : 0;
    r += (sj.w > val || (sj.w == val && (j + 3) < i)) ? 1 : 0;
  }
  rsum[t & 63][jc] = r;
  __syncthreads();
  if (t < 64) {
    int rank = rsum[t][0] + rsum[t][1] + rsum[t][2] + rsum[t][3];
    if (rank < M) idx[b * M + rank] = blockIdx.x * 64 + t;
  }
}

// ---- out partials via bf16 MFMA: m-tile 64 -> 512 blocks, 2/CU --------
// rinv computed inline with the exact rowred bits (same sum order + 1/s).
__global__ __launch_bounds__(256) void out_kernel(
    const float* __restrict__ Ae, const float* __restrict__ rowpart,
    const ushort_t* __restrict__ vbf, const int* __restrict__ idx,
    float* __restrict__ part) {
  __shared__ ushort_t sc[64][72];    // scores bf16, stride 144B (16B-aligned)
  __shared__ ushort_t vt[128][72];   // v bf16
  __shared__ int ridx[64];
  __shared__ float rinv[64];
  int t = threadIdx.x;
  int m0 = blockIdx.x * 64;
  int ns = blockIdx.y;
  int b = blockIdx.z;
  if (t < 64) {
    int r = idx[b * M + m0 + t];
    ridx[t] = r;
    float s = 0.f;
    #pragma unroll
    for (int sl = 0; sl < MBLK; ++sl)
      s += rowpart[(size_t)sl * (B * N) + b * N + r];
    rinv[t] = 1.0f / s;
  }
  __syncthreads();
  int lane = t & 63, w = t >> 6;
  int wc = w & 1, wm = w >> 1;       // c-half (64ch), m-half (32)
  int lr = lane & 31, lq = lane >> 5;
  f32x16 acc[2] = {};                // ct over two 32-ch subtiles
  int nbeg = ns * (N / NSPLIT);      // 256-wide K range
  for (int kb = 0; kb < N / NSPLIT; kb += 64) {
    __syncthreads();
    #pragma unroll
    for (int it = 0; it < 16; ++it) {   // scores: 64 rows x 64 cols
      int ii = it * 256 + t;            // 0..4095
      int r = ii >> 6, cn = ii & 63;
      float sv = Ae[((size_t)b * N + ridx[r]) * N + nbeg + kb + cn] * rinv[r];
      sc[r][cn] = f2bf(sv);
    }
    #pragma unroll
    for (int it = 0; it < 4; ++it) {    // v: 128 rows x 64 cols, short8 copies
      int u = it * 256 + t;             // 0..1023 vec-units
      int r = u >> 3, seg = u & 7;
      *(short8*)&vt[r][seg * 8] =
          *(const short8*)&vbf[((size_t)b * C + r) * N + nbeg + kb + seg * 8];
    }
    __syncthreads();
    #pragma unroll
    for (int ks = 0; ks < 4; ++ks) {
      short8 bf_ = *(const short8*)&sc[wm * 32 + lr][ks * 16 + lq * 8];
      #pragma unroll
      for (int ct = 0; ct < 2; ++ct) {
        short8 af = *(const short8*)&vt[wc * 64 + ct * 32 + lr][ks * 16 + lq * 8];
        acc[ct] = __builtin_amdgcn_mfma_f32_32x32x16_bf16(af, bf_, acc[ct], 0, 0, 0);
      }
    }
  }
  float* pb = part + ((size_t)ns * B + b) * C * M;
  #pragma unroll
  for (int ct = 0; ct < 2; ++ct) {
    #pragma unroll
    for (int reg = 0; reg < 16; ++reg) {
      int crow = wc * 64 + ct * 32 + (reg & 3) + 8 * (reg >> 2) + 4 * lq;
      pb[(size_t)crow * M + m0 + wm * 32 + lr] = acc[ct][reg];
    }
  }
}

// ---- deterministic reduce of the n-splits (float4, same per-elem order) --
__global__ __launch_bounds__(256) void reduce_kernel(
    const float* __restrict__ part, float* __restrict__ out) {
  int i = (blockIdx.x * 256 + threadIdx.x) * 4;
  float4 a = make_float4(0.f, 0.f, 0.f, 0.f);
  #pragma unroll
  for (int ns = 0; ns < NSPLIT; ++ns) {
    float4 p = *(const float4*)&part[(size_t)ns * (B * C * M) + i];
    a.x += p.x; a.y += p.y; a.z += p.z; a.w += p.w;
  }
  *(float4*)&out[i] = a;
}

extern "C" void kernel_launch(void* const* d_in, const int* in_sizes, int n_in,
                              void* d_out, int out_size, void* d_ws, size_t ws_size,
                              hipStream_t stream) {
  const float* x  = (const float*)d_in[0];
  const float* Wq = (const float*)d_in[1];
  const float* Wk = (const float*)d_in[2];
  const float* Wv = (const float*)d_in[3];
  float* out = (float*)d_out;

  const size_t TSZ = (size_t)B * N * C;
  ushort_t* split = (ushort_t*)d_ws;                 // 6 * TSZ bf16 = 25.2 MB
  ushort_t* vbf   = split + 6 * TSZ;                 // TSZ bf16 = 4.2 MB
  float* Ae       = (float*)(vbf + TSZ);             // 134.2 MB
  float* rowpart  = Ae + (size_t)B * N * N;          // 16 * B*N
  float* selpart  = rowpart + (size_t)MBLK * B * N;  // 8 * B*N
  int*   idx      = (int*)(selpart + (size_t)8 * B * N);  // B*M
  // part overlays split only (dead after energy); vbf stays live for out_kernel
  float* part     = (float*)split;

  qkv_kernel<<<dim3(16, N / 256, B), 256, 0, stream>>>(x, Wq, Wk, Wv, split, vbf);
  energy_kernel<<<dim3(N / 128, N / 128, B), 256, 0, stream>>>(split, Ae, rowpart);
  colsum_kernel<<<dim3(N / 256, 8, B), 256, 0, stream>>>(Ae, rowpart, selpart);
  topk_kernel<<<dim3(N / 64, B), 256, 0, stream>>>(selpart, idx);
  out_kernel<<<dim3(M / 64, NSPLIT, B), 256, 0, stream>>>(Ae, rowpart, vbf, idx, part);
  reduce_kernel<<<dim3(B * C * M / 1024), 256, 0, stream>>>(part, out);
}

// Round 14
// 236.098 us; speedup vs baseline: 1.0702x; 1.0702x over previous
//
#include <hip/hip_runtime.h>
#include <math.h>

namespace {
constexpr int B = 8, C = 128, N = 2048, M = 512;
constexpr int NSPLIT = 8;       // part (NSPLIT*B*C*M fp32 = 16.8MB) must fit split region (25.2MB)
constexpr int MBLK = 16;        // energy m-tiles -> rowpart slots
constexpr float INV_SQRT_C = 0.08838834764831845f;  // 1/sqrt(128)
}

typedef __attribute__((ext_vector_type(8))) short short8;
typedef __attribute__((ext_vector_type(16))) float f32x16;
typedef unsigned short ushort_t;
typedef unsigned int u32;

__device__ inline ushort_t f2bf(float f) {   // round-to-nearest-even bf16
  union { float f; u32 u; } a; a.f = f;
  u32 r = a.u + 0x7fffu + ((a.u >> 16) & 1u);
  return (ushort_t)(r >> 16);
}
__device__ inline float bf2f(ushort_t h) {
  union { u32 u; float f; } a; a.u = ((u32)h) << 16; return a.f;
}

// -- q,k: 3-term bf16 split, k-chunk-major [term][b][kc][n][8]; v: bf16 [b][c][n] --
__global__ __launch_bounds__(256) void qkv_kernel(
    const float* __restrict__ x, const float* __restrict__ Wq,
    const float* __restrict__ Wk, const float* __restrict__ Wv,
    ushort_t* __restrict__ split, ushort_t* __restrict__ vbf) {
  const size_t TERM = (size_t)B * N * C;
  int kc = blockIdx.x;             // output-channel chunk (8 channels)
  int o0 = kc * 8;
  int n = blockIdx.y * 256 + threadIdx.x;
  int b = blockIdx.z;
  const float* xb = x + (size_t)b * C * N + n;
  float aq[8] = {}, ak[8] = {}, av[8] = {};
  #pragma unroll 4
  for (int c = 0; c < C; ++c) {
    float xv = xb[(size_t)c * N];
    #pragma unroll
    for (int j = 0; j < 8; ++j) {   // W loads wave-uniform -> s_loads
      aq[j] = fmaf(Wq[(o0 + j) * C + c], xv, aq[j]);
      ak[j] = fmaf(Wk[(o0 + j) * C + c], xv, ak[j]);
      av[j] = fmaf(Wv[(o0 + j) * C + c], xv, av[j]);
    }
  }
  #pragma unroll
  for (int j = 0; j < 8; ++j)
    vbf[((size_t)b * C + o0 + j) * N + n] = f2bf(av[j]);
  size_t rowoff = ((size_t)b * 16 + kc) * (size_t)N * 8 + (size_t)n * 8;
  #pragma unroll
  for (int tt = 0; tt < 3; ++tt) {
    short8 qv, kv;
    #pragma unroll
    for (int j = 0; j < 8; ++j) {
      ushort_t h = f2bf(aq[j]); qv[j] = (short)h; aq[j] -= bf2f(h);
      h = f2bf(ak[j]);          kv[j] = (short)h; ak[j] -= bf2f(h);
    }
    *(short8*)&split[tt * TERM + rowoff]       = qv;
    *(short8*)&split[(3 + tt) * TERM + rowoff] = kv;
  }
}

// ---- Ae[b,n,m] = exp(q.k/sqrt(C)) via 6-product 3-term-split MFMA ------
// FROZEN (r5/r10 text verbatim): selection-path bits depend on this exact
// arithmetic order. Do not reorder MFMAs, exp, or the LDS reduce.
__global__ __launch_bounds__(256) void energy_kernel(
    const ushort_t* __restrict__ split,
    float* __restrict__ Ae, float* __restrict__ rowpart) {
  __shared__ float red[128][64];   // 32 KB
  __shared__ float red2[128][2];
  const size_t TERM = (size_t)B * N * C;
  const size_t ROW8 = (size_t)N * 8;       // elements per kc-row
  int t = threadIdx.x;
  int lane = t & 63, w = t >> 6;
  int wn = w & 1, wm = w >> 1;             // wave quadrant
  // 4x4 supertile swizzle for L2 locality
  int lin = blockIdx.y * 16 + blockIdx.x;
  int st = lin >> 4, wi = lin & 15;
  int mb = (st & 3) * 4 + (wi & 3);
  int nb = (st >> 2) * 4 + (wi >> 2);
  int m0 = mb * 128, n0 = nb * 128, b = blockIdx.z;
  int lr = lane & 31, lq = lane >> 5;
  size_t kbase = ((size_t)b * 16 + lq) * ROW8;
  const ushort_t* Abase = split + kbase + (size_t)(n0 + wn * 64 + lr) * 8;
  const ushort_t* Bbase = split + 3 * TERM + kbase + (size_t)(m0 + wm * 64 + lr) * 8;
  f32x16 acc[2][2] = {};
  #pragma unroll
  for (int s = 0; s < 8; ++s) {            // K = 8 steps x 16
    size_t so = (size_t)s * 2 * ROW8;
    short8 aT[3][2], bT[3][2];
    #pragma unroll
    for (int tt = 0; tt < 3; ++tt)
      #pragma unroll
      for (int i = 0; i < 2; ++i) {        // i = 32-point sub-tile
        aT[tt][i] = *(const short8*)(Abase + tt * TERM + so + i * 256);
        bT[tt][i] = *(const short8*)(Bbase + tt * TERM + so + i * 256);
      }
    #pragma unroll
    for (int mt = 0; mt < 2; ++mt)
      #pragma unroll
      for (int nt = 0; nt < 2; ++nt) {
        acc[mt][nt] = __builtin_amdgcn_mfma_f32_32x32x16_bf16(aT[0][mt], bT[0][nt], acc[mt][nt], 0, 0, 0);
        acc[mt][nt] = __builtin_amdgcn_mfma_f32_32x32x16_bf16(aT[1][mt], bT[0][nt], acc[mt][nt], 0, 0, 0);
        acc[mt][nt] = __builtin_amdgcn_mfma_f32_32x32x16_bf16(aT[0][mt], bT[1][nt], acc[mt][nt], 0, 0, 0);
        acc[mt][nt] = __builtin_amdgcn_mfma_f32_32x32x16_bf16(aT[2][mt], bT[0][nt], acc[mt][nt], 0, 0, 0);
        acc[mt][nt] = __builtin_amdgcn_mfma_f32_32x32x16_bf16(aT[1][mt], bT[1][nt], acc[mt][nt], 0, 0, 0);
        acc[mt][nt] = __builtin_amdgcn_mfma_f32_32x32x16_bf16(aT[0][mt], bT[2][nt], acc[mt][nt], 0, 0, 0);
      }
  }
  int lc = lr;
  #pragma unroll
  for (int mt = 0; mt < 2; ++mt) {
    #pragma unroll
    for (int reg = 0; reg < 16; ++reg) {
      int row = (reg & 3) + 8 * (reg >> 2) + 4 * lq;   // C/D layout (m74/m101)
      int rloc = wn * 64 + mt * 32 + row;
      float e0 = expf(acc[mt][0][reg] * INV_SQRT_C);
      float e1 = expf(acc[mt][1][reg] * INV_SQRT_C);
      float* pA = Ae + ((size_t)b * N + n0 + rloc) * N + m0 + wm * 64 + lc;
      pA[0] = e0; pA[32] = e1;
      red[rloc][wm * 32 + lc] = e0 + e1;   // disjoint slots, no race
    }
  }
  __syncthreads();
  {
    int row = t >> 1, h = t & 1;
    float ssum = 0.f;
    #pragma unroll
    for (int j0 = 0; j0 < 32; ++j0) {
      int j = (j0 + (t & 31)) & 31;        // bank rotation: 2-way max (free)
      ssum += red[row][h * 32 + j];
    }
    red2[row][h] = ssum;
  }
  __syncthreads();
  if (t < 128)
    rowpart[(size_t)mb * (B * N) + b * N + n0 + t] = red2[t][0] + red2[t][1];
}

// --- selpart[nch][b*N+m] = sum_{n in chunk} Ae[b,n,m] * invr[b,n] ------
// FROZEN arithmetic. invr computed inline with the exact rowred bits
// (ascending 16-slot fp32 sum, then 1/s); fmaf chain order unchanged.
__global__ __launch_bounds__(256) void colsum_kernel(
    const float* __restrict__ Ae, const float* __restrict__ rowpart,
    float* __restrict__ selpart) {
  __shared__ float sinv[256];
  int t = threadIdx.x;
  int m = blockIdx.x * 256 + t;
  int nch = blockIdx.y, b = blockIdx.z;
  int n0 = nch * (N / 8);
  {
    int n = n0 + t;                  // 256 threads <-> 256 chunk rows
    float s = 0.f;
    #pragma unroll
    for (int sl = 0; sl < MBLK; ++sl)
      s += rowpart[(size_t)sl * (B * N) + b * N + n];
    sinv[t] = 1.0f / s;
  }
  __syncthreads();
  const float* Ab = Ae + (size_t)b * N * N;
  float acc = 0.f;
  #pragma unroll 8
  for (int n = n0; n < n0 + N / 8; ++n)
    acc = fmaf(Ab[(size_t)n * N + m], sinv[n - n0], acc);
  selpart[(size_t)nch * (B * N) + b * N + m] = acc;
}

// -- exact stable-descending top-k; selred fused with the SAME ascending
// 8-chunk sum order as r5's selred (bit-identical sel) -------------------
__global__ __launch_bounds__(256) void topk_kernel(
    const float* __restrict__ selpart, int* __restrict__ idx) {
  __shared__ float s[N];
  __shared__ int rsum[64][4];
  int b = blockIdx.y;
  int t = threadIdx.x;
  for (int i = t; i < N; i += 256) {
    float v_ = 0.f;
    #pragma unroll
    for (int nch = 0; nch < 8; ++nch)
      v_ += selpart[(size_t)nch * (B * N) + b * N + i];
    s[i] = v_;
  }
  __syncthreads();
  int i = blockIdx.x * 64 + (t & 63);
  int jc = t >> 6;
  float val = s[i];
  int r = 0;
  for (int j = jc * 512; j < jc * 512 + 512; ++j) {
    float sj = s[j];
    r += (sj > val || (sj == val && j < i)) ? 1 : 0;
  }
  rsum[t & 63][jc] = r;
  __syncthreads();
  if (t < 64) {
    int rank = rsum[t][0] + rsum[t][1] + rsum[t][2] + rsum[t][3];
    if (rank < M) idx[b * M + rank] = blockIdx.x * 64 + t;
  }
}

// ---- out partials via bf16 MFMA: m-tile 64 -> 512 blocks, 2/CU --------
// rinv computed inline with the exact rowred bits (same sum order + 1/s).
__global__ __launch_bounds__(256) void out_kernel(
    const float* __restrict__ Ae, const float* __restrict__ rowpart,
    const ushort_t* __restrict__ vbf, const int* __restrict__ idx,
    float* __restrict__ part) {
  __shared__ ushort_t sc[64][72];    // scores bf16, stride 144B (16B-aligned)
  __shared__ ushort_t vt[128][72];   // v bf16
  __shared__ int ridx[64];
  __shared__ float rinv[64];
  int t = threadIdx.x;
  int m0 = blockIdx.x * 64;
  int ns = blockIdx.y;
  int b = blockIdx.z;
  if (t < 64) {
    int r = idx[b * M + m0 + t];
    ridx[t] = r;
    float s = 0.f;
    #pragma unroll
    for (int sl = 0; sl < MBLK; ++sl)
      s += rowpart[(size_t)sl * (B * N) + b * N + r];
    rinv[t] = 1.0f / s;
  }
  __syncthreads();
  int lane = t & 63, w = t >> 6;
  int wc = w & 1, wm = w >> 1;       // c-half (64ch), m-half (32)
  int lr = lane & 31, lq = lane >> 5;
  f32x16 acc[2] = {};                // ct over two 32-ch subtiles
  int nbeg = ns * (N / NSPLIT);      // 256-wide K range
  for (int kb = 0; kb < N / NSPLIT; kb += 64) {
    __syncthreads();
    #pragma unroll
    for (int it = 0; it < 16; ++it) {   // scores: 64 rows x 64 cols
      int ii = it * 256 + t;            // 0..4095
      int r = ii >> 6, cn = ii & 63;
      float sv = Ae[((size_t)b * N + ridx[r]) * N + nbeg + kb + cn] * rinv[r];
      sc[r][cn] = f2bf(sv);
    }
    #pragma unroll
    for (int it = 0; it < 4; ++it) {    // v: 128 rows x 64 cols, short8 copies
      int u = it * 256 + t;             // 0..1023 vec-units
      int r = u >> 3, seg = u & 7;
      *(short8*)&vt[r][seg * 8] =
          *(const short8*)&vbf[((size_t)b * C + r) * N + nbeg + kb + seg * 8];
    }
    __syncthreads();
    #pragma unroll
    for (int ks = 0; ks < 4; ++ks) {
      short8 bf_ = *(const short8*)&sc[wm * 32 + lr][ks * 16 + lq * 8];
      #pragma unroll
      for (int ct = 0; ct < 2; ++ct) {
        short8 af = *(const short8*)&vt[wc * 64 + ct * 32 + lr][ks * 16 + lq * 8];
        acc[ct] = __builtin_amdgcn_mfma_f32_32x32x16_bf16(af, bf_, acc[ct], 0, 0, 0);
      }
    }
  }
  float* pb = part + ((size_t)ns * B + b) * C * M;
  #pragma unroll
  for (int ct = 0; ct < 2; ++ct) {
    #pragma unroll
    for (int reg = 0; reg < 16; ++reg) {
      int crow = wc * 64 + ct * 32 + (reg & 3) + 8 * (reg >> 2) + 4 * lq;
      pb[(size_t)crow * M + m0 + wm * 32 + lr] = acc[ct][reg];
    }
  }
}

// ---- deterministic reduce of the n-splits (float4, same per-elem order) --
__global__ __launch_bounds__(256) void reduce_kernel(
    const float* __restrict__ part, float* __restrict__ out) {
  int i = (blockIdx.x * 256 + threadIdx.x) * 4;
  float4 a = make_float4(0.f, 0.f, 0.f, 0.f);
  #pragma unroll
  for (int ns = 0; ns < NSPLIT; ++ns) {
    float4 p = *(const float4*)&part[(size_t)ns * (B * C * M) + i];
    a.x += p.x; a.y += p.y; a.z += p.z; a.w += p.w;
  }
  *(float4*)&out[i] = a;
}

extern "C" void kernel_launch(void* const* d_in, const int* in_sizes, int n_in,
                              void* d_out, int out_size, void* d_ws, size_t ws_size,
                              hipStream_t stream) {
  const float* x  = (const float*)d_in[0];
  const float* Wq = (const float*)d_in[1];
  const float* Wk = (const float*)d_in[2];
  const float* Wv = (const float*)d_in[3];
  float* out = (float*)d_out;

  const size_t TSZ = (size_t)B * N * C;
  ushort_t* split = (ushort_t*)d_ws;                 // 6 * TSZ bf16 = 25.2 MB
  ushort_t* vbf   = split + 6 * TSZ;                 // TSZ bf16 = 4.2 MB
  float* Ae       = (float*)(vbf + TSZ);             // 134.2 MB
  float* rowpart  = Ae + (size_t)B * N * N;          // 16 * B*N
  float* selpart  = rowpart + (size_t)MBLK * B * N;  // 8 * B*N
  int*   idx      = (int*)(selpart + (size_t)8 * B * N);  // B*M
  // part overlays split only (dead after energy); vbf stays live for out_kernel
  float* part     = (float*)split;

  qkv_kernel<<<dim3(16, N / 256, B), 256, 0, stream>>>(x, Wq, Wk, Wv, split, vbf);
  energy_kernel<<<dim3(N / 128, N / 128, B), 256, 0, stream>>>(split, Ae, rowpart);
  colsum_kernel<<<dim3(N / 256, 8, B), 256, 0, stream>>>(Ae, rowpart, selpart);
  topk_kernel<<<dim3(N / 64, B), 256, 0, stream>>>(selpart, idx);
  out_kernel<<<dim3(M / 64, NSPLIT, B), 256, 0, stream>>>(Ae, rowpart, vbf, idx, part);
  reduce_kernel<<<dim3(B * C * M / 1024), 256, 0, stream>>>(part, out);
}